// Round 1
// baseline (421.765 us; speedup 1.0000x reference)
//
#include <hip/hip_runtime.h>
#include <hip/hip_bf16.h>
#include <stdint.h>

#define B_   2
#define S_   2048
#define H_   2048
#define NH_  16
#define HD_  128
#define MTOT (B_*S_)   // 4096

typedef __attribute__((ext_vector_type(8))) short bf16x8;   // 8 bf16 = 4 VGPRs
typedef __attribute__((ext_vector_type(4))) short bf16x4;   // 8B packed store
typedef __attribute__((ext_vector_type(4))) float f32x4;    // MFMA C/D

__device__ __forceinline__ void gload_lds16(const void* g, void* l) {
    __builtin_amdgcn_global_load_lds(
        (const __attribute__((address_space(1))) void*)g,
        (__attribute__((address_space(3))) void*)l, 16, 0, 0);
}

__device__ __forceinline__ unsigned short f2bfu(float x) {
    __hip_bfloat16 h = __float2bfloat16(x);
    return *reinterpret_cast<unsigned short*>(&h);
}
__device__ __forceinline__ int packbf(float a, float b) {
    return (int)f2bfu(a) | ((int)f2bfu(b) << 16);
}

#define BAR()  asm volatile("s_barrier" ::: "memory")
#define WLG0() asm volatile("s_waitcnt lgkmcnt(0)" ::: "memory")
#define WVM(n) asm volatile("s_waitcnt vmcnt(" #n ")" ::: "memory")

// ---------------------------------------------------------------- casts fp32 -> bf16
__global__ void castk(const float* __restrict__ in, __hip_bfloat16* __restrict__ out, int n4) {
    int i = blockIdx.x * 256 + threadIdx.x;
    if (i < n4) {
        float4 v = *(const float4*)(in + (size_t)i * 4);
        out[(size_t)i*4 + 0] = __float2bfloat16(v.x);
        out[(size_t)i*4 + 1] = __float2bfloat16(v.y);
        out[(size_t)i*4 + 2] = __float2bfloat16(v.z);
        out[(size_t)i*4 + 3] = __float2bfloat16(v.w);
    }
}

__global__ void castw4(const float* __restrict__ w0, const float* __restrict__ w1,
                       const float* __restrict__ w2, const float* __restrict__ w3,
                       __hip_bfloat16* o0, __hip_bfloat16* o1,
                       __hip_bfloat16* o2, __hip_bfloat16* o3, int n4) {
    const float* in; __hip_bfloat16* out;
    switch (blockIdx.y) {
        case 0:  in = w0; out = o0; break;
        case 1:  in = w1; out = o1; break;
        case 2:  in = w2; out = o2; break;
        default: in = w3; out = o3; break;
    }
    int i = blockIdx.x * 256 + threadIdx.x;
    if (i < n4) {
        float4 v = *(const float4*)(in + (size_t)i * 4);
        out[(size_t)i*4 + 0] = __float2bfloat16(v.x);
        out[(size_t)i*4 + 1] = __float2bfloat16(v.y);
        out[(size_t)i*4 + 2] = __float2bfloat16(v.z);
        out[(size_t)i*4 + 3] = __float2bfloat16(v.w);
    }
}

// ---------------------------------------------------------------- NT-GEMM body (m97 structure, kept for gemm_out)
template<int SMEMB, int BF16OUT>
__device__ __forceinline__ void gemm_body(const __hip_bfloat16* __restrict__ Ablk,
                                          const __hip_bfloat16* __restrict__ Wblk,
                                          const float* __restrict__ bias,
                                          void* __restrict__ Cout,
                                          int N, int K, int br, int bc, bool vt)
{
    __shared__ __align__(16) char smem[SMEMB];
    __hip_bfloat16* As = (__hip_bfloat16*)smem;             // 128x32, 8192 B
    __hip_bfloat16* Bs = (__hip_bfloat16*)(smem + 8192);    // 128x32, 8192 B

    const int tid  = threadIdx.x;
    const int wave = tid >> 6, lane = tid & 63;
    const int quad = lane >> 4, l16 = lane & 15;
    const int wr = wave >> 1, wc = wave & 1;

    f32x4 acc[4][4] = {};

    for (int k0 = 0; k0 < K; k0 += 32) {
#pragma unroll
        for (int t = 0; t < 2; ++t) {
            int c = t * 256 + wave * 64 + lane;
            int row = c >> 2, cc = c & 3;
            int base = (t * 256 + wave * 64) * 16;       // wave-uniform
            gload_lds16(Ablk + (size_t)row * K + k0 + cc * 8, (char*)As + base);
            gload_lds16(Wblk + (size_t)row * K + k0 + cc * 8, (char*)Bs + base);
        }
        __syncthreads();

        bf16x8 af[4], bf[4];
#pragma unroll
        for (int i = 0; i < 4; ++i)
            af[i] = *(const bf16x8*)&As[(wr * 64 + i * 16 + l16) * 32 + quad * 8];
#pragma unroll
        for (int j = 0; j < 4; ++j)
            bf[j] = *(const bf16x8*)&Bs[(wc * 64 + j * 16 + l16) * 32 + quad * 8];

#pragma unroll
        for (int i = 0; i < 4; ++i)
#pragma unroll
            for (int j = 0; j < 4; ++j)
                acc[i][j] = __builtin_amdgcn_mfma_f32_16x16x32_bf16(af[i], bf[j], acc[i][j], 0, 0, 0);
        __syncthreads();
    }

    if (BF16OUT && vt) {
        __hip_bfloat16* Ls = (__hip_bfloat16*)smem;   // 128*136*2 = 34816 B
#pragma unroll
        for (int j = 0; j < 4; ++j) {
            int d = wc * 64 + j * 16 + l16;
            float bv = bias[bc * 128 + d];
#pragma unroll
            for (int i = 0; i < 4; ++i) {
                int t0 = wr * 64 + i * 16 + quad * 4;
#pragma unroll
                for (int r = 0; r < 4; ++r)
                    Ls[d * 136 + t0 + r] = __float2bfloat16(acc[i][j][r] + bv);
            }
        }
        __syncthreads();
        const int bq = br >> 4;
        const int s0 = (br & 15) * 128;
        __hip_bfloat16* VT = (__hip_bfloat16*)Cout;
        const size_t rowbase = (size_t)(bq * 16 + bc) * 128;
#pragma unroll
        for (int rep = 0; rep < 8; ++rep) {
            int L = rep * 256 + tid;
            int d = L >> 4, tch = L & 15;
            bf16x8 v = *(const bf16x8*)&Ls[d * 136 + tch * 8];
            *(bf16x8*)(VT + (rowbase + d) * (size_t)S_ + s0 + tch * 8) = v;
        }
        return;
    }

#pragma unroll
    for (int i = 0; i < 4; ++i) {
        int row = br * 128 + wr * 64 + i * 16 + quad * 4;
#pragma unroll
        for (int j = 0; j < 4; ++j) {
            int col = bc * 128 + wc * 64 + j * 16 + l16;
            float bv = bias[col];
#pragma unroll
            for (int r = 0; r < 4; ++r) {
                float v = acc[i][j][r] + bv;
                if (BF16OUT)
                    ((__hip_bfloat16*)Cout)[(size_t)(row + r) * N + col] = __float2bfloat16(v);
                else
                    ((float*)Cout)[(size_t)(row + r) * N + col] = v;
            }
        }
    }
}

// O-projection: fp32 out (m97 structure, 512 blocks — grid-quantization makes 8-phase a wash here)
__global__ __launch_bounds__(256)
void gemm_out(const __hip_bfloat16* __restrict__ A, const __hip_bfloat16* __restrict__ W,
              const float* __restrict__ bias, float* __restrict__ C)
{
    gemm_body<16384, 0>(A + (size_t)(blockIdx.y * 128) * H_, W + (size_t)(blockIdx.x * 128) * H_,
                        bias, C, H_, H_, blockIdx.y, blockIdx.x, false);
}

// ---------------------------------------------------------------- fused QKV, 256x256 8-phase schedule
// 384 blocks x 512 thr (8 waves, 2Mx4N), BK=64, 128 KiB LDS double-buffer,
// st_16x32 swizzle (linear DMA dest + inverse-swizzled global src + swizzled ds_read),
// counted vmcnt(4) at phases 4/8 only (never 0 mid-loop), setprio around MFMA clusters.
//
// LDS map: buf0-A [0,32K) | buf1-A [32K,64K) | buf0-B [64K,96K) | buf1-B [96K,128K)
//          each buf = 2 halves of 128 rows x 64 K-cols bf16 (16 KiB), subtiled 16x32.
// Stage map (iter j computes tiles 2j [buf0] then 2j+1 [buf1]):
//   ph1: A(2j+1)->buf1A   ph2/ph3: B(2j+2)->buf0B   ph4: vmcnt(4)
//   ph5/ph6: A(2j+2)->buf0A   ph7/ph8: B(2j+3)->buf1B  ph8: vmcnt(4)
// Deadline check: every region's last-read precedes its stage issue (barrier-separated),
// and each vmcnt(4) retires everything except the newest 2 half-tiles, which are not
// read until after the next vmcnt(4). Last iteration: ph4 drains with vmcnt(0).
__global__ __launch_bounds__(512, 2)
void gemm_qkv8(const __hip_bfloat16* __restrict__ X,
               const __hip_bfloat16* __restrict__ Wq, const __hip_bfloat16* __restrict__ Wk,
               const __hip_bfloat16* __restrict__ Wv,
               const float* __restrict__ bq, const float* __restrict__ bk,
               const float* __restrict__ bv,
               __hip_bfloat16* __restrict__ Qo, __hip_bfloat16* __restrict__ Ko,
               __hip_bfloat16* __restrict__ VTo)
{
    __shared__ __align__(16) char smem[131072];

    // bijective XCD swizzle (384 % 8 == 0); bm fastest -> 48-block chunk shares 3 B-panels (3MB < 4MB L2)
    const int bid = blockIdx.x;
    const int swz = (bid & 7) * 48 + (bid >> 3);
    const int sel = swz >> 7;            // 0=Q 1=K 2=V
    const int rem = swz & 127;
    const int bm  = rem & 15;            // M tile 0..15
    const int bn  = rem >> 4;            // N tile 0..7

    const __hip_bfloat16* W = (sel == 0) ? Wq : (sel == 1) ? Wk : Wv;
    const float* bias       = (sel == 0) ? bq : (sel == 1) ? bk : bv;

    const int tid  = threadIdx.x;
    const int wave = tid >> 6, lane = tid & 63;
    const int quad = lane >> 4, l16 = lane & 15;
    const int wr = wave >> 2, wc = wave & 3;       // 2 x 4 wave grid

    // fragment-read offsets (swizzled): subtile = (rg*2+kk)*1024, row = l16*64,
    // col bytes XOR 32 in the upper 8 rows of each 16-row subtile
    const int ro = l16 * 64;
    const int co = (((l16 & 8) ? ((quad * 8) ^ 16) : (quad * 8)) << 1);

    // staging decomposition: linear LDS dest D -> inverse-swizzled global (row,col)
    int r0, c0, r1, c1;
    {
        int D = tid * 16;                          // round 0: bytes [0,8K)
        int rg = D >> 11, cg = (D >> 10) & 1;
        int rr = (D >> 6) & 15, c = (D & 63) >> 1;
        int cs = (rr & 8) ? (c ^ 16) : c;
        r0 = rg * 16 + rr;  c0 = cg * 32 + cs;
        D = 8192 + tid * 16;                       // round 1: bytes [8K,16K)
        rg = D >> 11; cg = (D >> 10) & 1;
        rr = (D >> 6) & 15; c = (D & 63) >> 1;
        cs = (rr & 8) ? (c ^ 16) : c;
        r1 = rg * 16 + rr;  c1 = cg * 32 + cs;
    }

    const __hip_bfloat16* Xp = X + (size_t)(bm * 256) * H_;
    const __hip_bfloat16* Wp = W + (size_t)(bn * 256) * H_;

    char* const A0h = smem + wr * 16384;                     // buf0-A, this wave's half
    char* const A1h = smem + 32768 + wr * 16384;             // buf1-A
    char* const B0h = smem + 65536 + (wc >> 1) * 16384;      // buf0-B
    char* const B1h = smem + 98304 + (wc >> 1) * 16384;      // buf1-B
    const int bsub = (wc & 1) * 4;                           // B subtile group within half

    auto STG = [&](char* ldsb, const __hip_bfloat16* g) {
        gload_lds16(g + (size_t)r0 * H_ + c0, ldsb + wave * 1024);
        gload_lds16(g + (size_t)r1 * H_ + c1, ldsb + 8192 + wave * 1024);
    };
    auto SRC = [&](const __hip_bfloat16* P, int t, int hf) {
        return P + (size_t)(hf * 128) * H_ + (size_t)t * 64;
    };

    f32x4 acc[8][4] = {};

    // prologue: tile0 (A+B) -> buf0, tile1 B -> buf1; tile1 A is staged at ph1 of iter 0
    STG(smem,                 SRC(Xp, 0, 0));
    STG(smem + 16384,         SRC(Xp, 0, 1));
    STG(smem + 65536,         SRC(Wp, 0, 0));
    STG(smem + 65536 + 16384, SRC(Wp, 0, 1));
    STG(smem + 98304,         SRC(Wp, 1, 0));
    STG(smem + 98304 + 16384, SRC(Wp, 1, 1));
    WVM(4);                    // tile0's 8 loads landed; tile1-B (4) still in flight
    BAR();

    const int NIT = H_ / 128;  // 16 iterations, 2 K-tiles each
    bf16x8 bfr[4][2];
    for (int j = 0; j < NIT; ++j) {
        const bool more = (j < NIT - 1);
        const int t1 = 2 * j + 1;
#pragma unroll
        for (int ph = 0; ph < 8; ++ph) {
            const int p = ph & 3;
            char* aA = (ph < 4) ? A0h : A1h;
            char* aB = (ph < 4) ? B0h : B1h;

            // ds reads: 8 B-frags on the first phase of each tile, 4 A-frags per phase
            if (p == 0) {
#pragma unroll
                for (int jj = 0; jj < 4; ++jj)
#pragma unroll
                    for (int kk = 0; kk < 2; ++kk)
                        bfr[jj][kk] = *(const bf16x8*)(aB + ((bsub + jj) * 2 + kk) * 1024 + ro + co);
            }
            bf16x8 af[2][2];
#pragma unroll
            for (int i2 = 0; i2 < 2; ++i2)
#pragma unroll
                for (int kk = 0; kk < 2; ++kk)
                    af[i2][kk] = *(const bf16x8*)(aA + ((2 * p + i2) * 2 + kk) * 1024 + ro + co);

            // stage one half-tile (issue-early; lands under later phases)
            if (ph == 0) { STG(smem + 32768, SRC(Xp, t1, 0));
                           STG(smem + 49152, SRC(Xp, t1, 1)); }
            else if (ph == 1 && more) STG(smem + 65536,          SRC(Wp, t1 + 1, 0));
            else if (ph == 2 && more) STG(smem + 65536 + 16384,  SRC(Wp, t1 + 1, 1));
            else if (ph == 4 && more) STG(smem,                  SRC(Xp, t1 + 1, 0));
            else if (ph == 5 && more) STG(smem + 16384,          SRC(Xp, t1 + 1, 1));
            else if (ph == 6 && more) STG(smem + 98304,          SRC(Wp, t1 + 2, 0));
            else if (ph == 7 && more) STG(smem + 98304 + 16384,  SRC(Wp, t1 + 2, 1));

            // counted waits: only at phase 4 / phase 8, never 0 mid-loop
            if (ph == 3) { if (more) { WVM(4); } else { WVM(0); } }
            if (ph == 7 && more) { WVM(4); }

            BAR();
            WLG0();
            __builtin_amdgcn_sched_barrier(0);
            __builtin_amdgcn_s_setprio(1);
#pragma unroll
            for (int kk = 0; kk < 2; ++kk)
#pragma unroll
                for (int i2 = 0; i2 < 2; ++i2)
#pragma unroll
                    for (int jj = 0; jj < 4; ++jj)
                        acc[2 * p + i2][jj] = __builtin_amdgcn_mfma_f32_16x16x32_bf16(
                            af[i2][kk], bfr[jj][kk], acc[2 * p + i2][jj], 0, 0, 0);
            __builtin_amdgcn_s_setprio(0);
            BAR();
        }
    }

    // epilogue: C[row = bm*256 + wr*128 + i*16 + quad*4 + r][col = bn*256 + wc*64 + jj*16 + l16]
    if (sel < 2) {
        __hip_bfloat16* out = (sel == 0) ? Qo : Ko;
#pragma unroll
        for (int i = 0; i < 8; ++i) {
            int row = bm * 256 + wr * 128 + i * 16 + quad * 4;
#pragma unroll
            for (int jj = 0; jj < 4; ++jj) {
                int col = bn * 256 + wc * 64 + jj * 16 + l16;
                float bv = bias[col];
#pragma unroll
                for (int r = 0; r < 4; ++r)
                    out[(size_t)(row + r) * H_ + col] = __float2bfloat16(acc[i][jj][r] + bv);
            }
        }
    } else {
        // V^T scattered store: 4 consecutive tokens per fragment are contiguous in VT rows
#pragma unroll
        for (int i = 0; i < 8; ++i) {
            int tok = bm * 256 + wr * 128 + i * 16 + quad * 4;
            int b = tok >> 11, s = tok & (S_ - 1);
#pragma unroll
            for (int jj = 0; jj < 4; ++jj) {
                int col = bn * 256 + wc * 64 + jj * 16 + l16;
                int h = col >> 7, d = col & 127;
                float bv = bias[col];
                bf16x4 v;
#pragma unroll
                for (int r = 0; r < 4; ++r)
                    v[r] = (short)f2bfu(acc[i][jj][r] + bv);
                *(bf16x4*)(VTo + ((size_t)(b * 16 + h) * 128 + d) * S_ + s) = v;
            }
        }
    }
}

// ---------------------------------------------------------------- flash attention v7 (+T5 setprio)
__global__ __launch_bounds__(256)
void attn_kernel(const __hip_bfloat16* __restrict__ Q,
                 const __hip_bfloat16* __restrict__ K,
                 const __hip_bfloat16* __restrict__ VT,   // [(b*16+h)*128 + d][s]
                 __hip_bfloat16* __restrict__ O)
{
    __shared__ __align__(16) char Ks[16384];   // K-tile: 64 key-rows x 256B
    __shared__ __align__(16) char Vt[16384];   // V^T-tile: 128 d-rows x 128B

    const int tid  = threadIdx.x;
    const int wave = tid >> 6, lane = tid & 63;
    const int quad = lane >> 4, l16 = lane & 15;

    const int lid = blockIdx.x;
    const int xcd = lid & 7;
    const int q   = lid >> 3;
    const int bh  = ((q >> 5) << 3) | xcd;
    const int qb  = 31 - (q & 31);
    const int b   = bh >> 4, h = bh & 15;

    const size_t headoff = (size_t)b * S_ * H_ + (size_t)h * HD_;
    const __hip_bfloat16* Qp  = Q + headoff;
    const __hip_bfloat16* Kp  = K + headoff;
    const __hip_bfloat16* Vtp = VT + (size_t)(b * 16 + h) * 128 * S_;

    const float scale = 0.08838834764831843f;
    const int A0 = (((quad & 1) * 2) * 16 + l16) * 4;
    const int A1 = A0 + 64;
    const bool hiq = (quad >= 2);

    const int qrow_local = wave * 16;
    const int qrow = qb * 64 + qrow_local;

    bf16x8 qf[4];
#pragma unroll
    for (int kd = 0; kd < 4; ++kd)
        qf[kd] = *(const bf16x8*)(Qp + (size_t)(qrow + l16) * H_ + kd * 32 + quad * 8);

    f32x4 oacc[8] = {};
    float mi = -1e30f, li = 0.0f;

#pragma unroll
    for (int t = 0; t < 4; ++t) {
        int c = wave * 256 + t * 64 + lane;
        int krow = c >> 4, kpos = c & 15;
        gload_lds16(Kp + (size_t)krow * H_ + (kpos ^ (krow & 7)) * 8,
                    &Ks[(wave * 256 + t * 64) * 16]);
        int vrow = c >> 3, vpos = c & 7;
        gload_lds16(Vtp + (size_t)vrow * S_ + (vpos ^ (vrow & 7)) * 8,
                    &Vt[(wave * 256 + t * 64) * 16]);
    }
    __syncthreads();

    for (int kb = 0; kb <= qb; ++kb) {
        const bool more = (kb < qb);

        f32x4 sacc[4] = {};
        __builtin_amdgcn_s_setprio(1);
#pragma unroll
        for (int cb = 0; cb < 4; ++cb) {
#pragma unroll
            for (int kd = 0; kd < 4; ++kd) {
                int row = cb * 16 + l16;
                int pos = (4 * kd + quad) ^ (l16 & 7);
                bf16x8 kf = *(const bf16x8*)&Ks[row * 256 + pos * 16];
                sacc[cb] = __builtin_amdgcn_mfma_f32_16x16x32_bf16(kf, qf[kd], sacc[cb], 0, 0, 0);
            }
        }
        __builtin_amdgcn_s_setprio(0);

        __syncthreads();

        if (more) {
            const __hip_bfloat16* Kn = Kp + (size_t)(kb + 1) * 64 * H_;
#pragma unroll
            for (int t = 0; t < 4; ++t) {
                int c = wave * 256 + t * 64 + lane;
                int krow = c >> 4, kpos = c & 15;
                gload_lds16(Kn + (size_t)krow * H_ + (kpos ^ (krow & 7)) * 8,
                            &Ks[(wave * 256 + t * 64) * 16]);
            }
        }

        const bool diag = (kb == qb);
        float p[4][4];
        float tm = -1e30f;
#pragma unroll
        for (int cb = 0; cb < 4; ++cb)
#pragma unroll
            for (int r = 0; r < 4; ++r) {
                float s = sacc[cb][r] * scale;
                if (diag) {
                    int keyl = cb * 16 + quad * 4 + r;
                    if (keyl > qrow_local + l16) s = -1e30f;
                }
                p[cb][r] = s;
                tm = fmaxf(tm, s);
            }
        tm = fmaxf(tm, __shfl_xor(tm, 16));
        tm = fmaxf(tm, __shfl_xor(tm, 32));
        float mnew = fmaxf(mi, tm);
        float sum = 0.0f;
#pragma unroll
        for (int cb = 0; cb < 4; ++cb)
#pragma unroll
            for (int r = 0; r < 4; ++r) {
                float e = __expf(p[cb][r] - mnew);
                p[cb][r] = e;
                sum += e;
            }
        sum += __shfl_xor(sum, 16);
        sum += __shfl_xor(sum, 32);
        float alpha = __expf(mi - mnew);
        li = li * alpha + sum;
        mi = mnew;

        float ar[4];
#pragma unroll
        for (int r = 0; r < 4; ++r)
            ar[r] = __shfl(alpha, quad * 4 + r);
#pragma unroll
        for (int db = 0; db < 8; ++db)
#pragma unroll
            for (int r = 0; r < 4; ++r)
                oacc[db][r] *= ar[r];

        int Pp[4][2];
#pragma unroll
        for (int cb = 0; cb < 4; ++cb) {
            Pp[cb][0] = packbf(p[cb][0], p[cb][1]);
            Pp[cb][1] = packbf(p[cb][2], p[cb][3]);
        }
        bf16x8 pf[2];
#pragma unroll
        for (int ks = 0; ks < 2; ++ks) {
            int c0 = 2 * ks, c1 = 2 * ks + 1;
            int d0 = __builtin_amdgcn_ds_bpermute(A0, Pp[c0][0]);
            int e0 = __builtin_amdgcn_ds_bpermute(A0, Pp[c1][0]);
            int d1 = __builtin_amdgcn_ds_bpermute(A0, Pp[c0][1]);
            int e1 = __builtin_amdgcn_ds_bpermute(A0, Pp[c1][1]);
            int d2 = __builtin_amdgcn_ds_bpermute(A1, Pp[c0][0]);
            int e2 = __builtin_amdgcn_ds_bpermute(A1, Pp[c1][0]);
            int d3 = __builtin_amdgcn_ds_bpermute(A1, Pp[c0][1]);
            int e3 = __builtin_amdgcn_ds_bpermute(A1, Pp[c1][1]);
            union { int i[4]; bf16x8 v; } u;
            u.i[0] = hiq ? e0 : d0;
            u.i[1] = hiq ? e1 : d1;
            u.i[2] = hiq ? e2 : d2;
            u.i[3] = hiq ? e3 : d3;
            pf[ks] = u.v;
        }

        __builtin_amdgcn_s_setprio(1);
#pragma unroll
        for (int ks = 0; ks < 2; ++ks) {
#pragma unroll
            for (int db = 0; db < 8; ++db) {
                int vrow = db * 16 + l16;
                int vpos = (ks * 4 + quad) ^ (l16 & 7);
                bf16x8 vf = *(const bf16x8*)&Vt[vrow * 128 + vpos * 16];
                oacc[db] = __builtin_amdgcn_mfma_f32_16x16x32_bf16(pf[ks], vf, oacc[db], 0, 0, 0);
            }
        }
        __builtin_amdgcn_s_setprio(0);

        __syncthreads();

        if (more) {
            const int vcol = (kb + 1) * 64;
#pragma unroll
            for (int t = 0; t < 4; ++t) {
                int c = wave * 256 + t * 64 + lane;
                int vrow = c >> 3, vpos = c & 7;
                gload_lds16(Vtp + (size_t)vrow * S_ + vcol + (vpos ^ (vrow & 7)) * 8,
                            &Vt[(wave * 256 + t * 64) * 16]);
            }
        }
    }

    float lr[4];
#pragma unroll
    for (int r = 0; r < 4; ++r)
        lr[r] = __shfl(li, quad * 4 + r);
#pragma unroll
    for (int db = 0; db < 8; ++db)
#pragma unroll
        for (int r = 0; r < 4; ++r) {
            float v = oacc[db][r] / lr[r];
            size_t row = (size_t)b * S_ + qrow + quad * 4 + r;
            O[row * H_ + h * HD_ + db * 16 + l16] = __float2bfloat16(v);
        }
}

// ---------------------------------------------------------------- launcher
extern "C" void kernel_launch(void* const* d_in, const int* in_sizes, int n_in,
                              void* d_out, int out_size, void* d_ws, size_t ws_size,
                              hipStream_t stream)
{
    const float* hs = (const float*)d_in[0];
    const float* Wq = (const float*)d_in[2];
    const float* bq = (const float*)d_in[3];
    const float* Wk = (const float*)d_in[4];
    const float* bk = (const float*)d_in[5];
    const float* Wv = (const float*)d_in[6];
    const float* bv = (const float*)d_in[7];
    const float* Wo = (const float*)d_in[8];
    const float* bo = (const float*)d_in[9];

    const size_t szX = (size_t)MTOT * H_;
    const size_t szW = (size_t)H_ * H_;

    __hip_bfloat16* Xbf = (__hip_bfloat16*)d_ws;   // reused as attention output
    __hip_bfloat16* Wqb = Xbf + szX;
    __hip_bfloat16* Wkb = Wqb + szW;
    __hip_bfloat16* Wvb = Wkb + szW;
    __hip_bfloat16* Wob = Wvb + szW;
    __hip_bfloat16* Qb  = Wob + szW;
    __hip_bfloat16* Kb  = Qb + szX;
    __hip_bfloat16* VTb = Kb + szX;                // V^T [(b*16+h)*128+d][s]

    castk<<<(int)((szX/4 + 255)/256), 256, 0, stream>>>(hs, Xbf, (int)(szX/4));
    dim3 wgrid((unsigned)((szW/4 + 255)/256), 4);
    castw4<<<wgrid, 256, 0, stream>>>(Wq, Wk, Wv, Wo, Wqb, Wkb, Wvb, Wob, (int)(szW/4));

    gemm_qkv8<<<dim3(384), 512, 0, stream>>>(Xbf, Wqb, Wkb, Wvb, bq, bk, bv, Qb, Kb, VTb);

    attn_kernel<<<dim3(1024), 256, 0, stream>>>(Qb, Kb, VTb, Xbf);

    gemm_out<<<dim3(16, 32), 256, 0, stream>>>(Xbf, Wob, bo, (float*)d_out);
}

// Round 2
// 419.573 us; speedup vs baseline: 1.0052x; 1.0052x over previous
//
#include <hip/hip_runtime.h>
#include <hip/hip_bf16.h>
#include <stdint.h>

#define B_   2
#define S_   2048
#define H_   2048
#define NH_  16
#define HD_  128
#define MTOT (B_*S_)   // 4096

typedef __attribute__((ext_vector_type(8))) short bf16x8;   // 8 bf16 = 4 VGPRs
typedef __attribute__((ext_vector_type(4))) short bf16x4;   // 8B packed store
typedef __attribute__((ext_vector_type(4))) float f32x4;    // MFMA C/D

__device__ __forceinline__ void gload_lds16(const void* g, void* l) {
    __builtin_amdgcn_global_load_lds(
        (const __attribute__((address_space(1))) void*)g,
        (__attribute__((address_space(3))) void*)l, 16, 0, 0);
}

__device__ __forceinline__ unsigned short f2bfu(float x) {
    __hip_bfloat16 h = __float2bfloat16(x);
    return *reinterpret_cast<unsigned short*>(&h);
}
__device__ __forceinline__ int packbf(float a, float b) {
    return (int)f2bfu(a) | ((int)f2bfu(b) << 16);
}

#define BAR()  asm volatile("s_barrier" ::: "memory")
#define WLG0() asm volatile("s_waitcnt lgkmcnt(0)" ::: "memory")
#define WVM(n) asm volatile("s_waitcnt vmcnt(" #n ")" ::: "memory")

// ---------------------------------------------------------------- casts fp32 -> bf16
__global__ void castk(const float* __restrict__ in, __hip_bfloat16* __restrict__ out, int n4) {
    int i = blockIdx.x * 256 + threadIdx.x;
    if (i < n4) {
        float4 v = *(const float4*)(in + (size_t)i * 4);
        out[(size_t)i*4 + 0] = __float2bfloat16(v.x);
        out[(size_t)i*4 + 1] = __float2bfloat16(v.y);
        out[(size_t)i*4 + 2] = __float2bfloat16(v.z);
        out[(size_t)i*4 + 3] = __float2bfloat16(v.w);
    }
}

__global__ void castw4(const float* __restrict__ w0, const float* __restrict__ w1,
                       const float* __restrict__ w2, const float* __restrict__ w3,
                       __hip_bfloat16* o0, __hip_bfloat16* o1,
                       __hip_bfloat16* o2, __hip_bfloat16* o3, int n4) {
    const float* in; __hip_bfloat16* out;
    switch (blockIdx.y) {
        case 0:  in = w0; out = o0; break;
        case 1:  in = w1; out = o1; break;
        case 2:  in = w2; out = o2; break;
        default: in = w3; out = o3; break;
    }
    int i = blockIdx.x * 256 + threadIdx.x;
    if (i < n4) {
        float4 v = *(const float4*)(in + (size_t)i * 4);
        out[(size_t)i*4 + 0] = __float2bfloat16(v.x);
        out[(size_t)i*4 + 1] = __float2bfloat16(v.y);
        out[(size_t)i*4 + 2] = __float2bfloat16(v.z);
        out[(size_t)i*4 + 3] = __float2bfloat16(v.w);
    }
}

// ---------------------------------------------------------------- 256x256 8-phase GEMM body
// (verified in round 1: bank-conflict 0, passed). BK=64, 8 waves (2Mx4N), 128 KiB LDS,
// st_16x32 swizzle, counted vmcnt(4) at phases 4/8, setprio around MFMA clusters.
// LDS map: buf0-A [0,32K) | buf1-A [32K,64K) | buf0-B [64K,96K) | buf1-B [96K,128K)
// Stage map (iter j computes tiles 2j [buf0] then 2j+1 [buf1]):
//   ph0: A(2j+1)->buf1A   ph1/ph2: B(2j+2)->buf0B   ph3: vmcnt(4)
//   ph4/ph5: A(2j+2)->buf0A   ph6/ph7: B(2j+3)->buf1B  ph7: vmcnt(4)
template<int EPI>   // 0 = fp32 row-major, 1 = bf16 row-major, 2 = bf16 V^T scatter
__device__ __forceinline__ void gemm256_body(const __hip_bfloat16* __restrict__ Xp,
                                             const __hip_bfloat16* __restrict__ Wp,
                                             const float* __restrict__ bias,
                                             void* __restrict__ Cout,
                                             int bm, int bn, char* smem)
{
    const int tid  = threadIdx.x;
    const int wave = tid >> 6, lane = tid & 63;
    const int quad = lane >> 4, l16 = lane & 15;
    const int wr = wave >> 2, wc = wave & 3;       // 2 x 4 wave grid

    // fragment-read offsets (swizzled)
    const int ro = l16 * 64;
    const int co = (((l16 & 8) ? ((quad * 8) ^ 16) : (quad * 8)) << 1);

    // staging decomposition: linear LDS dest D -> inverse-swizzled global (row,col)
    int r0, c0, r1, c1;
    {
        int D = tid * 16;
        int rg = D >> 11, cg = (D >> 10) & 1;
        int rr = (D >> 6) & 15, c = (D & 63) >> 1;
        int cs = (rr & 8) ? (c ^ 16) : c;
        r0 = rg * 16 + rr;  c0 = cg * 32 + cs;
        D = 8192 + tid * 16;
        rg = D >> 11; cg = (D >> 10) & 1;
        rr = (D >> 6) & 15; c = (D & 63) >> 1;
        cs = (rr & 8) ? (c ^ 16) : c;
        r1 = rg * 16 + rr;  c1 = cg * 32 + cs;
    }

    char* const A0h = smem + wr * 16384;
    char* const A1h = smem + 32768 + wr * 16384;
    char* const B0h = smem + 65536 + (wc >> 1) * 16384;
    char* const B1h = smem + 98304 + (wc >> 1) * 16384;
    const int bsub = (wc & 1) * 4;

    auto STG = [&](char* ldsb, const __hip_bfloat16* g) {
        gload_lds16(g + (size_t)r0 * H_ + c0, ldsb + wave * 1024);
        gload_lds16(g + (size_t)r1 * H_ + c1, ldsb + 8192 + wave * 1024);
    };
    auto SRC = [&](const __hip_bfloat16* P, int t, int hf) {
        return P + (size_t)(hf * 128) * H_ + (size_t)t * 64;
    };

    f32x4 acc[8][4] = {};

    STG(smem,                 SRC(Xp, 0, 0));
    STG(smem + 16384,         SRC(Xp, 0, 1));
    STG(smem + 65536,         SRC(Wp, 0, 0));
    STG(smem + 65536 + 16384, SRC(Wp, 0, 1));
    STG(smem + 98304,         SRC(Wp, 1, 0));
    STG(smem + 98304 + 16384, SRC(Wp, 1, 1));
    WVM(4);
    BAR();

    const int NIT = H_ / 128;  // 16 iterations, 2 K-tiles each
    bf16x8 bfr[4][2];
    for (int j = 0; j < NIT; ++j) {
        const bool more = (j < NIT - 1);
        const int t1 = 2 * j + 1;
#pragma unroll
        for (int ph = 0; ph < 8; ++ph) {
            const int p = ph & 3;
            char* aA = (ph < 4) ? A0h : A1h;
            char* aB = (ph < 4) ? B0h : B1h;

            if (p == 0) {
#pragma unroll
                for (int jj = 0; jj < 4; ++jj)
#pragma unroll
                    for (int kk = 0; kk < 2; ++kk)
                        bfr[jj][kk] = *(const bf16x8*)(aB + ((bsub + jj) * 2 + kk) * 1024 + ro + co);
            }
            bf16x8 af[2][2];
#pragma unroll
            for (int i2 = 0; i2 < 2; ++i2)
#pragma unroll
                for (int kk = 0; kk < 2; ++kk)
                    af[i2][kk] = *(const bf16x8*)(aA + ((2 * p + i2) * 2 + kk) * 1024 + ro + co);

            if (ph == 0) { STG(smem + 32768, SRC(Xp, t1, 0));
                           STG(smem + 49152, SRC(Xp, t1, 1)); }
            else if (ph == 1 && more) STG(smem + 65536,          SRC(Wp, t1 + 1, 0));
            else if (ph == 2 && more) STG(smem + 65536 + 16384,  SRC(Wp, t1 + 1, 1));
            else if (ph == 4 && more) STG(smem,                  SRC(Xp, t1 + 1, 0));
            else if (ph == 5 && more) STG(smem + 16384,          SRC(Xp, t1 + 1, 1));
            else if (ph == 6 && more) STG(smem + 98304,          SRC(Wp, t1 + 2, 0));
            else if (ph == 7 && more) STG(smem + 98304 + 16384,  SRC(Wp, t1 + 2, 1));

            if (ph == 3) { if (more) { WVM(4); } else { WVM(0); } }
            if (ph == 7 && more) { WVM(4); }

            BAR();
            WLG0();
            __builtin_amdgcn_sched_barrier(0);
            __builtin_amdgcn_s_setprio(1);
#pragma unroll
            for (int kk = 0; kk < 2; ++kk)
#pragma unroll
                for (int i2 = 0; i2 < 2; ++i2)
#pragma unroll
                    for (int jj = 0; jj < 4; ++jj)
                        acc[2 * p + i2][jj] = __builtin_amdgcn_mfma_f32_16x16x32_bf16(
                            af[i2][kk], bfr[jj][kk], acc[2 * p + i2][jj], 0, 0, 0);
            __builtin_amdgcn_s_setprio(0);
            BAR();
        }
    }

    if (EPI == 2) {
        // V^T scattered store: 4 consecutive tokens per fragment are contiguous in VT rows
        __hip_bfloat16* VTo = (__hip_bfloat16*)Cout;
#pragma unroll
        for (int i = 0; i < 8; ++i) {
            int tok = bm * 256 + wr * 128 + i * 16 + quad * 4;
            int b = tok >> 11, s = tok & (S_ - 1);
#pragma unroll
            for (int jj = 0; jj < 4; ++jj) {
                int col = bn * 256 + wc * 64 + jj * 16 + l16;
                int h = col >> 7, d = col & 127;
                float bv = bias[col];
                bf16x4 v;
#pragma unroll
                for (int r = 0; r < 4; ++r)
                    v[r] = (short)f2bfu(acc[i][jj][r] + bv);
                *(bf16x4*)(VTo + ((size_t)(b * 16 + h) * 128 + d) * S_ + s) = v;
            }
        }
    } else {
#pragma unroll
        for (int i = 0; i < 8; ++i) {
            int row = bm * 256 + wr * 128 + i * 16 + quad * 4;
#pragma unroll
            for (int jj = 0; jj < 4; ++jj) {
                int col = bn * 256 + wc * 64 + jj * 16 + l16;
                float bv = bias[col];
#pragma unroll
                for (int r = 0; r < 4; ++r) {
                    float v = acc[i][jj][r] + bv;
                    if (EPI == 1)
                        ((__hip_bfloat16*)Cout)[(size_t)(row + r) * H_ + col] = __float2bfloat16(v);
                    else
                        ((float*)Cout)[(size_t)(row + r) * H_ + col] = v;
                }
            }
        }
    }
}

// fused QKV: 384 blocks (known 1.5-round tail; deferred)
__global__ __launch_bounds__(512, 2)
void gemm_qkv8(const __hip_bfloat16* __restrict__ X,
               const __hip_bfloat16* __restrict__ Wq, const __hip_bfloat16* __restrict__ Wk,
               const __hip_bfloat16* __restrict__ Wv,
               const float* __restrict__ bq, const float* __restrict__ bk,
               const float* __restrict__ bv,
               __hip_bfloat16* __restrict__ Qo, __hip_bfloat16* __restrict__ Ko,
               __hip_bfloat16* __restrict__ VTo)
{
    __shared__ __align__(16) char smem[131072];

    const int bid = blockIdx.x;
    const int swz = (bid & 7) * 48 + (bid >> 3);
    const int sel = swz >> 7;            // 0=Q 1=K 2=V
    const int rem = swz & 127;
    const int bm  = rem & 15;
    const int bn  = rem >> 4;

    const __hip_bfloat16* W = (sel == 0) ? Wq : (sel == 1) ? Wk : Wv;
    const float* bias       = (sel == 0) ? bq : (sel == 1) ? bk : bv;

    const __hip_bfloat16* Xp = X + (size_t)(bm * 256) * H_;
    const __hip_bfloat16* Wp = W + (size_t)(bn * 256) * H_;

    if (sel == 2)
        gemm256_body<2>(Xp, Wp, bias, VTo, bm, bn, smem);
    else
        gemm256_body<1>(Xp, Wp, bias, (sel == 0) ? Qo : Ko, bm, bn, smem);
}

// O-projection: 128 blocks of 256x256, fp32 out. Half-machine but ~2x the m97 per-CU rate.
__global__ __launch_bounds__(512, 2)
void gemm_out8(const __hip_bfloat16* __restrict__ A, const __hip_bfloat16* __restrict__ W,
               const float* __restrict__ bias, float* __restrict__ C)
{
    __shared__ __align__(16) char smem[131072];
    // bijective XCD swizzle, 4bm x 4bn chunk per XCD (8 MB footprint)
    const int bid = blockIdx.x;          // 0..127
    const int xcd = bid & 7, i = bid >> 3;
    const int bm  = (xcd & 3) * 4 + (i & 3);
    const int bn  = (xcd >> 2) * 4 + (i >> 2);
    gemm256_body<0>(A + (size_t)(bm * 256) * H_, W + (size_t)(bn * 256) * H_,
                    bias, C, bm, bn, smem);
}

// ---------------------------------------------------------------- flash attention v7 (round-0 form)
__global__ __launch_bounds__(256)
void attn_kernel(const __hip_bfloat16* __restrict__ Q,
                 const __hip_bfloat16* __restrict__ K,
                 const __hip_bfloat16* __restrict__ VT,   // [(b*16+h)*128 + d][s]
                 __hip_bfloat16* __restrict__ O)
{
    __shared__ __align__(16) char Ks[16384];   // K-tile: 64 key-rows x 256B
    __shared__ __align__(16) char Vt[16384];   // V^T-tile: 128 d-rows x 128B

    const int tid  = threadIdx.x;
    const int wave = tid >> 6, lane = tid & 63;
    const int quad = lane >> 4, l16 = lane & 15;

    const int lid = blockIdx.x;
    const int xcd = lid & 7;
    const int q   = lid >> 3;
    const int bh  = ((q >> 5) << 3) | xcd;
    const int qb  = 31 - (q & 31);
    const int b   = bh >> 4, h = bh & 15;

    const size_t headoff = (size_t)b * S_ * H_ + (size_t)h * HD_;
    const __hip_bfloat16* Qp  = Q + headoff;
    const __hip_bfloat16* Kp  = K + headoff;
    const __hip_bfloat16* Vtp = VT + (size_t)(b * 16 + h) * 128 * S_;

    const float scale = 0.08838834764831843f;
    const int A0 = (((quad & 1) * 2) * 16 + l16) * 4;
    const int A1 = A0 + 64;
    const bool hiq = (quad >= 2);

    const int qrow_local = wave * 16;
    const int qrow = qb * 64 + qrow_local;

    bf16x8 qf[4];
#pragma unroll
    for (int kd = 0; kd < 4; ++kd)
        qf[kd] = *(const bf16x8*)(Qp + (size_t)(qrow + l16) * H_ + kd * 32 + quad * 8);

    f32x4 oacc[8] = {};
    float mi = -1e30f, li = 0.0f;

#pragma unroll
    for (int t = 0; t < 4; ++t) {
        int c = wave * 256 + t * 64 + lane;
        int krow = c >> 4, kpos = c & 15;
        gload_lds16(Kp + (size_t)krow * H_ + (kpos ^ (krow & 7)) * 8,
                    &Ks[(wave * 256 + t * 64) * 16]);
        int vrow = c >> 3, vpos = c & 7;
        gload_lds16(Vtp + (size_t)vrow * S_ + (vpos ^ (vrow & 7)) * 8,
                    &Vt[(wave * 256 + t * 64) * 16]);
    }
    __syncthreads();

    for (int kb = 0; kb <= qb; ++kb) {
        const bool more = (kb < qb);

        f32x4 sacc[4] = {};
#pragma unroll
        for (int cb = 0; cb < 4; ++cb) {
#pragma unroll
            for (int kd = 0; kd < 4; ++kd) {
                int row = cb * 16 + l16;
                int pos = (4 * kd + quad) ^ (l16 & 7);
                bf16x8 kf = *(const bf16x8*)&Ks[row * 256 + pos * 16];
                sacc[cb] = __builtin_amdgcn_mfma_f32_16x16x32_bf16(kf, qf[kd], sacc[cb], 0, 0, 0);
            }
        }

        __syncthreads();

        if (more) {
            const __hip_bfloat16* Kn = Kp + (size_t)(kb + 1) * 64 * H_;
#pragma unroll
            for (int t = 0; t < 4; ++t) {
                int c = wave * 256 + t * 64 + lane;
                int krow = c >> 4, kpos = c & 15;
                gload_lds16(Kn + (size_t)krow * H_ + (kpos ^ (krow & 7)) * 8,
                            &Ks[(wave * 256 + t * 64) * 16]);
            }
        }

        const bool diag = (kb == qb);
        float p[4][4];
        float tm = -1e30f;
#pragma unroll
        for (int cb = 0; cb < 4; ++cb)
#pragma unroll
            for (int r = 0; r < 4; ++r) {
                float s = sacc[cb][r] * scale;
                if (diag) {
                    int keyl = cb * 16 + quad * 4 + r;
                    if (keyl > qrow_local + l16) s = -1e30f;
                }
                p[cb][r] = s;
                tm = fmaxf(tm, s);
            }
        tm = fmaxf(tm, __shfl_xor(tm, 16));
        tm = fmaxf(tm, __shfl_xor(tm, 32));
        float mnew = fmaxf(mi, tm);
        float sum = 0.0f;
#pragma unroll
        for (int cb = 0; cb < 4; ++cb)
#pragma unroll
            for (int r = 0; r < 4; ++r) {
                float e = __expf(p[cb][r] - mnew);
                p[cb][r] = e;
                sum += e;
            }
        sum += __shfl_xor(sum, 16);
        sum += __shfl_xor(sum, 32);
        float alpha = __expf(mi - mnew);
        li = li * alpha + sum;
        mi = mnew;

        float ar[4];
#pragma unroll
        for (int r = 0; r < 4; ++r)
            ar[r] = __shfl(alpha, quad * 4 + r);
#pragma unroll
        for (int db = 0; db < 8; ++db)
#pragma unroll
            for (int r = 0; r < 4; ++r)
                oacc[db][r] *= ar[r];

        int Pp[4][2];
#pragma unroll
        for (int cb = 0; cb < 4; ++cb) {
            Pp[cb][0] = packbf(p[cb][0], p[cb][1]);
            Pp[cb][1] = packbf(p[cb][2], p[cb][3]);
        }
        bf16x8 pf[2];
#pragma unroll
        for (int ks = 0; ks < 2; ++ks) {
            int c0 = 2 * ks, c1 = 2 * ks + 1;
            int d0 = __builtin_amdgcn_ds_bpermute(A0, Pp[c0][0]);
            int e0 = __builtin_amdgcn_ds_bpermute(A0, Pp[c1][0]);
            int d1 = __builtin_amdgcn_ds_bpermute(A0, Pp[c0][1]);
            int e1 = __builtin_amdgcn_ds_bpermute(A0, Pp[c1][1]);
            int d2 = __builtin_amdgcn_ds_bpermute(A1, Pp[c0][0]);
            int e2 = __builtin_amdgcn_ds_bpermute(A1, Pp[c1][0]);
            int d3 = __builtin_amdgcn_ds_bpermute(A1, Pp[c0][1]);
            int e3 = __builtin_amdgcn_ds_bpermute(A1, Pp[c1][1]);
            union { int i[4]; bf16x8 v; } u;
            u.i[0] = hiq ? e0 : d0;
            u.i[1] = hiq ? e1 : d1;
            u.i[2] = hiq ? e2 : d2;
            u.i[3] = hiq ? e3 : d3;
            pf[ks] = u.v;
        }

#pragma unroll
        for (int ks = 0; ks < 2; ++ks) {
#pragma unroll
            for (int db = 0; db < 8; ++db) {
                int vrow = db * 16 + l16;
                int vpos = (ks * 4 + quad) ^ (l16 & 7);
                bf16x8 vf = *(const bf16x8*)&Vt[vrow * 128 + vpos * 16];
                oacc[db] = __builtin_amdgcn_mfma_f32_16x16x32_bf16(pf[ks], vf, oacc[db], 0, 0, 0);
            }
        }

        __syncthreads();

        if (more) {
            const int vcol = (kb + 1) * 64;
#pragma unroll
            for (int t = 0; t < 4; ++t) {
                int c = wave * 256 + t * 64 + lane;
                int vrow = c >> 3, vpos = c & 7;
                gload_lds16(Vtp + (size_t)vrow * S_ + vcol + (vpos ^ (vrow & 7)) * 8,
                            &Vt[(wave * 256 + t * 64) * 16]);
            }
        }
    }

    float lr[4];
#pragma unroll
    for (int r = 0; r < 4; ++r)
        lr[r] = __shfl(li, quad * 4 + r);
#pragma unroll
    for (int db = 0; db < 8; ++db)
#pragma unroll
        for (int r = 0; r < 4; ++r) {
            float v = oacc[db][r] / lr[r];
            size_t row = (size_t)b * S_ + qrow + quad * 4 + r;
            O[row * H_ + h * HD_ + db * 16 + l16] = __float2bfloat16(v);
        }
}

// ---------------------------------------------------------------- launcher
extern "C" void kernel_launch(void* const* d_in, const int* in_sizes, int n_in,
                              void* d_out, int out_size, void* d_ws, size_t ws_size,
                              hipStream_t stream)
{
    const float* hs = (const float*)d_in[0];
    const float* Wq = (const float*)d_in[2];
    const float* bq = (const float*)d_in[3];
    const float* Wk = (const float*)d_in[4];
    const float* bk = (const float*)d_in[5];
    const float* Wv = (const float*)d_in[6];
    const float* bv = (const float*)d_in[7];
    const float* Wo = (const float*)d_in[8];
    const float* bo = (const float*)d_in[9];

    const size_t szX = (size_t)MTOT * H_;
    const size_t szW = (size_t)H_ * H_;

    __hip_bfloat16* Xbf = (__hip_bfloat16*)d_ws;   // reused as attention output
    __hip_bfloat16* Wqb = Xbf + szX;
    __hip_bfloat16* Wkb = Wqb + szW;
    __hip_bfloat16* Wvb = Wkb + szW;
    __hip_bfloat16* Wob = Wvb + szW;
    __hip_bfloat16* Qb  = Wob + szW;
    __hip_bfloat16* Kb  = Qb + szX;
    __hip_bfloat16* VTb = Kb + szX;                // V^T [(b*16+h)*128+d][s]

    castk<<<(int)((szX/4 + 255)/256), 256, 0, stream>>>(hs, Xbf, (int)(szX/4));
    dim3 wgrid((unsigned)((szW/4 + 255)/256), 4);
    castw4<<<wgrid, 256, 0, stream>>>(Wq, Wk, Wv, Wo, Wqb, Wkb, Wvb, Wob, (int)(szW/4));

    gemm_qkv8<<<dim3(384), 512, 0, stream>>>(Xbf, Wqb, Wkb, Wvb, bq, bk, bv, Qb, Kb, VTb);

    attn_kernel<<<dim3(1024), 256, 0, stream>>>(Qb, Kb, VTb, Xbf);

    gemm_out8<<<dim3(128), 512, 0, stream>>>(Xbf, Wob, bo, (float*)d_out);
}

// Round 3
// 406.923 us; speedup vs baseline: 1.0365x; 1.0311x over previous
//
#include <hip/hip_runtime.h>
#include <hip/hip_bf16.h>
#include <stdint.h>

#define B_   2
#define S_   2048
#define H_   2048
#define NH_  16
#define HD_  128
#define MTOT (B_*S_)   // 4096

typedef __attribute__((ext_vector_type(8))) short bf16x8;   // 8 bf16 = 4 VGPRs
typedef __attribute__((ext_vector_type(4))) short bf16x4;   // 8B packed store
typedef __attribute__((ext_vector_type(4))) float f32x4;    // MFMA C/D

__device__ __forceinline__ void gload_lds16(const void* g, void* l) {
    __builtin_amdgcn_global_load_lds(
        (const __attribute__((address_space(1))) void*)g,
        (__attribute__((address_space(3))) void*)l, 16, 0, 0);
}

__device__ __forceinline__ unsigned short f2bfu(float x) {
    __hip_bfloat16 h = __float2bfloat16(x);
    return *reinterpret_cast<unsigned short*>(&h);
}
__device__ __forceinline__ int packbf(float a, float b) {
    return (int)f2bfu(a) | ((int)f2bfu(b) << 16);
}

#define BAR()  asm volatile("s_barrier" ::: "memory")
#define WLG0() asm volatile("s_waitcnt lgkmcnt(0)" ::: "memory")
#define WVM(n) asm volatile("s_waitcnt vmcnt(" #n ")" ::: "memory")

// ---------------------------------------------------------------- fused fp32 -> bf16 casts
// 6 equal regions of 1048576 float4s: X (2 halves) + 4 weight matrices. Exact grid, no bounds.
__global__ void castall(const float* __restrict__ hs,
                        const float* __restrict__ w0, const float* __restrict__ w1,
                        const float* __restrict__ w2, const float* __restrict__ w3,
                        __hip_bfloat16* __restrict__ xb,
                        __hip_bfloat16* __restrict__ o0, __hip_bfloat16* __restrict__ o1,
                        __hip_bfloat16* __restrict__ o2, __hip_bfloat16* __restrict__ o3)
{
    const size_t Q = 1048576;   // float4s per region
    const float* in; __hip_bfloat16* out; size_t base;
    switch (blockIdx.y) {
        case 0:  in = hs; out = xb; base = 0; break;
        case 1:  in = hs; out = xb; base = Q; break;
        case 2:  in = w0; out = o0; base = 0; break;
        case 3:  in = w1; out = o1; base = 0; break;
        case 4:  in = w2; out = o2; base = 0; break;
        default: in = w3; out = o3; base = 0; break;
    }
    size_t i = base + (size_t)blockIdx.x * 256 + threadIdx.x;
    float4 v = *(const float4*)(in + i * 4);
    out[i*4 + 0] = __float2bfloat16(v.x);
    out[i*4 + 1] = __float2bfloat16(v.y);
    out[i*4 + 2] = __float2bfloat16(v.z);
    out[i*4 + 3] = __float2bfloat16(v.w);
}

// ---------------------------------------------------------------- NT-GEMM body (m97 structure, for gemm_out)
template<int SMEMB, int BF16OUT>
__device__ __forceinline__ void gemm_body(const __hip_bfloat16* __restrict__ Ablk,
                                          const __hip_bfloat16* __restrict__ Wblk,
                                          const float* __restrict__ bias,
                                          void* __restrict__ Cout,
                                          int N, int K, int br, int bc)
{
    __shared__ __align__(16) char smem[SMEMB];
    __hip_bfloat16* As = (__hip_bfloat16*)smem;             // 128x32, 8192 B
    __hip_bfloat16* Bs = (__hip_bfloat16*)(smem + 8192);    // 128x32, 8192 B

    const int tid  = threadIdx.x;
    const int wave = tid >> 6, lane = tid & 63;
    const int quad = lane >> 4, l16 = lane & 15;
    const int wr = wave >> 1, wc = wave & 1;

    f32x4 acc[4][4] = {};

    for (int k0 = 0; k0 < K; k0 += 32) {
#pragma unroll
        for (int t = 0; t < 2; ++t) {
            int c = t * 256 + wave * 64 + lane;
            int row = c >> 2, cc = c & 3;
            int base = (t * 256 + wave * 64) * 16;       // wave-uniform
            gload_lds16(Ablk + (size_t)row * K + k0 + cc * 8, (char*)As + base);
            gload_lds16(Wblk + (size_t)row * K + k0 + cc * 8, (char*)Bs + base);
        }
        __syncthreads();

        bf16x8 af[4], bf[4];
#pragma unroll
        for (int i = 0; i < 4; ++i)
            af[i] = *(const bf16x8*)&As[(wr * 64 + i * 16 + l16) * 32 + quad * 8];
#pragma unroll
        for (int j = 0; j < 4; ++j)
            bf[j] = *(const bf16x8*)&Bs[(wc * 64 + j * 16 + l16) * 32 + quad * 8];

#pragma unroll
        for (int i = 0; i < 4; ++i)
#pragma unroll
            for (int j = 0; j < 4; ++j)
                acc[i][j] = __builtin_amdgcn_mfma_f32_16x16x32_bf16(af[i], bf[j], acc[i][j], 0, 0, 0);
        __syncthreads();
    }

#pragma unroll
    for (int i = 0; i < 4; ++i) {
        int row = br * 128 + wr * 64 + i * 16 + quad * 4;
#pragma unroll
        for (int j = 0; j < 4; ++j) {
            int col = bc * 128 + wc * 64 + j * 16 + l16;
            float bv = bias[col];
#pragma unroll
            for (int r = 0; r < 4; ++r) {
                float v = acc[i][j][r] + bv;
                if (BF16OUT)
                    ((__hip_bfloat16*)Cout)[(size_t)(row + r) * N + col] = __float2bfloat16(v);
                else
                    ((float*)Cout)[(size_t)(row + r) * N + col] = v;
            }
        }
    }
}

// O-projection: fp32 out, 512 blocks (full machine; beats half-idle 8-phase per round-2 A/B)
__global__ __launch_bounds__(256)
void gemm_out(const __hip_bfloat16* __restrict__ A, const __hip_bfloat16* __restrict__ W,
              const float* __restrict__ bias, float* __restrict__ C)
{
    gemm_body<16384, 0>(A + (size_t)(blockIdx.y * 128) * H_, W + (size_t)(blockIdx.x * 128) * H_,
                        bias, C, H_, H_, blockIdx.y, blockIdx.x);
}

// ---------------------------------------------------------------- 256x256 8-phase GEMM body (qkv)
// verified rounds 1-2: bank-conflict 0, passed. BK=64, 8 waves (2Mx4N), 128 KiB LDS,
// st_16x32 swizzle, counted vmcnt(4) at phases 4/8, setprio around MFMA clusters.
template<int EPI>   // 1 = bf16 row-major, 2 = bf16 V^T scatter
__device__ __forceinline__ void gemm256_body(const __hip_bfloat16* __restrict__ Xp,
                                             const __hip_bfloat16* __restrict__ Wp,
                                             const float* __restrict__ bias,
                                             void* __restrict__ Cout,
                                             int bm, int bn, char* smem)
{
    const int tid  = threadIdx.x;
    const int wave = tid >> 6, lane = tid & 63;
    const int quad = lane >> 4, l16 = lane & 15;
    const int wr = wave >> 2, wc = wave & 3;       // 2 x 4 wave grid

    const int ro = l16 * 64;
    const int co = (((l16 & 8) ? ((quad * 8) ^ 16) : (quad * 8)) << 1);

    int r0, c0, r1, c1;
    {
        int D = tid * 16;
        int rg = D >> 11, cg = (D >> 10) & 1;
        int rr = (D >> 6) & 15, c = (D & 63) >> 1;
        int cs = (rr & 8) ? (c ^ 16) : c;
        r0 = rg * 16 + rr;  c0 = cg * 32 + cs;
        D = 8192 + tid * 16;
        rg = D >> 11; cg = (D >> 10) & 1;
        rr = (D >> 6) & 15; c = (D & 63) >> 1;
        cs = (rr & 8) ? (c ^ 16) : c;
        r1 = rg * 16 + rr;  c1 = cg * 32 + cs;
    }

    char* const A0h = smem + wr * 16384;
    char* const A1h = smem + 32768 + wr * 16384;
    char* const B0h = smem + 65536 + (wc >> 1) * 16384;
    char* const B1h = smem + 98304 + (wc >> 1) * 16384;
    const int bsub = (wc & 1) * 4;

    auto STG = [&](char* ldsb, const __hip_bfloat16* g) {
        gload_lds16(g + (size_t)r0 * H_ + c0, ldsb + wave * 1024);
        gload_lds16(g + (size_t)r1 * H_ + c1, ldsb + 8192 + wave * 1024);
    };
    auto SRC = [&](const __hip_bfloat16* P, int t, int hf) {
        return P + (size_t)(hf * 128) * H_ + (size_t)t * 64;
    };

    f32x4 acc[8][4] = {};

    STG(smem,                 SRC(Xp, 0, 0));
    STG(smem + 16384,         SRC(Xp, 0, 1));
    STG(smem + 65536,         SRC(Wp, 0, 0));
    STG(smem + 65536 + 16384, SRC(Wp, 0, 1));
    STG(smem + 98304,         SRC(Wp, 1, 0));
    STG(smem + 98304 + 16384, SRC(Wp, 1, 1));
    WVM(4);
    BAR();

    const int NIT = H_ / 128;  // 16 iterations, 2 K-tiles each
    bf16x8 bfr[4][2];
    for (int j = 0; j < NIT; ++j) {
        const bool more = (j < NIT - 1);
        const int t1 = 2 * j + 1;
#pragma unroll
        for (int ph = 0; ph < 8; ++ph) {
            const int p = ph & 3;
            char* aA = (ph < 4) ? A0h : A1h;
            char* aB = (ph < 4) ? B0h : B1h;

            if (p == 0) {
#pragma unroll
                for (int jj = 0; jj < 4; ++jj)
#pragma unroll
                    for (int kk = 0; kk < 2; ++kk)
                        bfr[jj][kk] = *(const bf16x8*)(aB + ((bsub + jj) * 2 + kk) * 1024 + ro + co);
            }
            bf16x8 af[2][2];
#pragma unroll
            for (int i2 = 0; i2 < 2; ++i2)
#pragma unroll
                for (int kk = 0; kk < 2; ++kk)
                    af[i2][kk] = *(const bf16x8*)(aA + ((2 * p + i2) * 2 + kk) * 1024 + ro + co);

            if (ph == 0) { STG(smem + 32768, SRC(Xp, t1, 0));
                           STG(smem + 49152, SRC(Xp, t1, 1)); }
            else if (ph == 1 && more) STG(smem + 65536,          SRC(Wp, t1 + 1, 0));
            else if (ph == 2 && more) STG(smem + 65536 + 16384,  SRC(Wp, t1 + 1, 1));
            else if (ph == 4 && more) STG(smem,                  SRC(Xp, t1 + 1, 0));
            else if (ph == 5 && more) STG(smem + 16384,          SRC(Xp, t1 + 1, 1));
            else if (ph == 6 && more) STG(smem + 98304,          SRC(Wp, t1 + 2, 0));
            else if (ph == 7 && more) STG(smem + 98304 + 16384,  SRC(Wp, t1 + 2, 1));

            if (ph == 3) { if (more) { WVM(4); } else { WVM(0); } }
            if (ph == 7 && more) { WVM(4); }

            BAR();
            WLG0();
            __builtin_amdgcn_sched_barrier(0);
            __builtin_amdgcn_s_setprio(1);
#pragma unroll
            for (int kk = 0; kk < 2; ++kk)
#pragma unroll
                for (int i2 = 0; i2 < 2; ++i2)
#pragma unroll
                    for (int jj = 0; jj < 4; ++jj)
                        acc[2 * p + i2][jj] = __builtin_amdgcn_mfma_f32_16x16x32_bf16(
                            af[i2][kk], bfr[jj][kk], acc[2 * p + i2][jj], 0, 0, 0);
            __builtin_amdgcn_s_setprio(0);
            BAR();
        }
    }

    if (EPI == 2) {
        __hip_bfloat16* VTo = (__hip_bfloat16*)Cout;
#pragma unroll
        for (int i = 0; i < 8; ++i) {
            int tok = bm * 256 + wr * 128 + i * 16 + quad * 4;
            int b = tok >> 11, s = tok & (S_ - 1);
#pragma unroll
            for (int jj = 0; jj < 4; ++jj) {
                int col = bn * 256 + wc * 64 + jj * 16 + l16;
                int h = col >> 7, d = col & 127;
                float bv = bias[col];
                bf16x4 v;
#pragma unroll
                for (int r = 0; r < 4; ++r)
                    v[r] = (short)f2bfu(acc[i][jj][r] + bv);
                *(bf16x4*)(VTo + ((size_t)(b * 16 + h) * 128 + d) * S_ + s) = v;
            }
        }
    } else {
#pragma unroll
        for (int i = 0; i < 8; ++i) {
            int row = bm * 256 + wr * 128 + i * 16 + quad * 4;
#pragma unroll
            for (int jj = 0; jj < 4; ++jj) {
                int col = bn * 256 + wc * 64 + jj * 16 + l16;
                float bv = bias[col];
#pragma unroll
                for (int r = 0; r < 4; ++r)
                    ((__hip_bfloat16*)Cout)[(size_t)(row + r) * H_ + col] =
                        __float2bfloat16(acc[i][jj][r] + bv);
            }
        }
    }
}

// fused QKV: 384 blocks (known 1.5-round tail; structural, deferred)
__global__ __launch_bounds__(512, 2)
void gemm_qkv8(const __hip_bfloat16* __restrict__ X,
               const __hip_bfloat16* __restrict__ Wq, const __hip_bfloat16* __restrict__ Wk,
               const __hip_bfloat16* __restrict__ Wv,
               const float* __restrict__ bq, const float* __restrict__ bk,
               const float* __restrict__ bv,
               __hip_bfloat16* __restrict__ Qo, __hip_bfloat16* __restrict__ Ko,
               __hip_bfloat16* __restrict__ VTo)
{
    __shared__ __align__(16) char smem[131072];

    const int bid = blockIdx.x;
    const int swz = (bid & 7) * 48 + (bid >> 3);
    const int sel = swz >> 7;            // 0=Q 1=K 2=V
    const int rem = swz & 127;
    const int bm  = rem & 15;
    const int bn  = rem >> 4;

    const __hip_bfloat16* W = (sel == 0) ? Wq : (sel == 1) ? Wk : Wv;
    const float* bias       = (sel == 0) ? bq : (sel == 1) ? bk : bv;

    const __hip_bfloat16* Xp = X + (size_t)(bm * 256) * H_;
    const __hip_bfloat16* Wp = W + (size_t)(bn * 256) * H_;

    if (sel == 2)
        gemm256_body<2>(Xp, Wp, bias, VTo, bm, bn, smem);
    else
        gemm256_body<1>(Xp, Wp, bias, (sel == 0) ? Qo : Ko, bm, bn, smem);
}

// ---------------------------------------------------------------- flash attention v7 + T13 defer-max
__global__ __launch_bounds__(256)
void attn_kernel(const __hip_bfloat16* __restrict__ Q,
                 const __hip_bfloat16* __restrict__ K,
                 const __hip_bfloat16* __restrict__ VT,   // [(b*16+h)*128 + d][s]
                 __hip_bfloat16* __restrict__ O)
{
    __shared__ __align__(16) char Ks[16384];   // K-tile: 64 key-rows x 256B
    __shared__ __align__(16) char Vt[16384];   // V^T-tile: 128 d-rows x 128B

    const int tid  = threadIdx.x;
    const int wave = tid >> 6, lane = tid & 63;
    const int quad = lane >> 4, l16 = lane & 15;

    const int lid = blockIdx.x;
    const int xcd = lid & 7;
    const int q   = lid >> 3;
    const int bh  = ((q >> 5) << 3) | xcd;
    const int qb  = 31 - (q & 31);
    const int b   = bh >> 4, h = bh & 15;

    const size_t headoff = (size_t)b * S_ * H_ + (size_t)h * HD_;
    const __hip_bfloat16* Qp  = Q + headoff;
    const __hip_bfloat16* Kp  = K + headoff;
    const __hip_bfloat16* Vtp = VT + (size_t)(b * 16 + h) * 128 * S_;

    const float scale = 0.08838834764831843f;
    const int A0 = (((quad & 1) * 2) * 16 + l16) * 4;
    const int A1 = A0 + 64;
    const bool hiq = (quad >= 2);

    const int qrow_local = wave * 16;
    const int qrow = qb * 64 + qrow_local;

    bf16x8 qf[4];
#pragma unroll
    for (int kd = 0; kd < 4; ++kd)
        qf[kd] = *(const bf16x8*)(Qp + (size_t)(qrow + l16) * H_ + kd * 32 + quad * 8);

    f32x4 oacc[8] = {};
    float mi = -1e30f, li = 0.0f;

#pragma unroll
    for (int t = 0; t < 4; ++t) {
        int c = wave * 256 + t * 64 + lane;
        int krow = c >> 4, kpos = c & 15;
        gload_lds16(Kp + (size_t)krow * H_ + (kpos ^ (krow & 7)) * 8,
                    &Ks[(wave * 256 + t * 64) * 16]);
        int vrow = c >> 3, vpos = c & 7;
        gload_lds16(Vtp + (size_t)vrow * S_ + (vpos ^ (vrow & 7)) * 8,
                    &Vt[(wave * 256 + t * 64) * 16]);
    }
    __syncthreads();

    for (int kb = 0; kb <= qb; ++kb) {
        const bool more = (kb < qb);

        f32x4 sacc[4] = {};
#pragma unroll
        for (int cb = 0; cb < 4; ++cb) {
#pragma unroll
            for (int kd = 0; kd < 4; ++kd) {
                int row = cb * 16 + l16;
                int pos = (4 * kd + quad) ^ (l16 & 7);
                bf16x8 kf = *(const bf16x8*)&Ks[row * 256 + pos * 16];
                sacc[cb] = __builtin_amdgcn_mfma_f32_16x16x32_bf16(kf, qf[kd], sacc[cb], 0, 0, 0);
            }
        }

        __syncthreads();

        if (more) {
            const __hip_bfloat16* Kn = Kp + (size_t)(kb + 1) * 64 * H_;
#pragma unroll
            for (int t = 0; t < 4; ++t) {
                int c = wave * 256 + t * 64 + lane;
                int krow = c >> 4, kpos = c & 15;
                gload_lds16(Kn + (size_t)krow * H_ + (kpos ^ (krow & 7)) * 8,
                            &Ks[(wave * 256 + t * 64) * 16]);
            }
        }

        const bool diag = (kb == qb);
        float p[4][4];
        float tm = -1e30f;
#pragma unroll
        for (int cb = 0; cb < 4; ++cb)
#pragma unroll
            for (int r = 0; r < 4; ++r) {
                float s = sacc[cb][r] * scale;
                if (diag) {
                    int keyl = cb * 16 + quad * 4 + r;
                    if (keyl > qrow_local + l16) s = -1e30f;
                }
                p[cb][r] = s;
                tm = fmaxf(tm, s);
            }
        tm = fmaxf(tm, __shfl_xor(tm, 16));
        tm = fmaxf(tm, __shfl_xor(tm, 32));

        // T13 defer-max: skip rescale when tile max doesn't exceed running max by >8
        const bool noresc = __all(tm - mi <= 8.0f);
        float mnew = noresc ? mi : fmaxf(mi, tm);

        float sum = 0.0f;
#pragma unroll
        for (int cb = 0; cb < 4; ++cb)
#pragma unroll
            for (int r = 0; r < 4; ++r) {
                float e = __expf(p[cb][r] - mnew);
                p[cb][r] = e;
                sum += e;
            }
        sum += __shfl_xor(sum, 16);
        sum += __shfl_xor(sum, 32);

        if (noresc) {
            li = li + sum;
        } else {
            float alpha = __expf(mi - mnew);
            li = li * alpha + sum;
            float ar[4];
#pragma unroll
            for (int r = 0; r < 4; ++r)
                ar[r] = __shfl(alpha, quad * 4 + r);
#pragma unroll
            for (int db = 0; db < 8; ++db)
#pragma unroll
                for (int r = 0; r < 4; ++r)
                    oacc[db][r] *= ar[r];
        }
        mi = mnew;

        int Pp[4][2];
#pragma unroll
        for (int cb = 0; cb < 4; ++cb) {
            Pp[cb][0] = packbf(p[cb][0], p[cb][1]);
            Pp[cb][1] = packbf(p[cb][2], p[cb][3]);
        }
        bf16x8 pf[2];
#pragma unroll
        for (int ks = 0; ks < 2; ++ks) {
            int c0 = 2 * ks, c1 = 2 * ks + 1;
            int d0 = __builtin_amdgcn_ds_bpermute(A0, Pp[c0][0]);
            int e0 = __builtin_amdgcn_ds_bpermute(A0, Pp[c1][0]);
            int d1 = __builtin_amdgcn_ds_bpermute(A0, Pp[c0][1]);
            int e1 = __builtin_amdgcn_ds_bpermute(A0, Pp[c1][1]);
            int d2 = __builtin_amdgcn_ds_bpermute(A1, Pp[c0][0]);
            int e2 = __builtin_amdgcn_ds_bpermute(A1, Pp[c1][0]);
            int d3 = __builtin_amdgcn_ds_bpermute(A1, Pp[c0][1]);
            int e3 = __builtin_amdgcn_ds_bpermute(A1, Pp[c1][1]);
            union { int i[4]; bf16x8 v; } u;
            u.i[0] = hiq ? e0 : d0;
            u.i[1] = hiq ? e1 : d1;
            u.i[2] = hiq ? e2 : d2;
            u.i[3] = hiq ? e3 : d3;
            pf[ks] = u.v;
        }

#pragma unroll
        for (int ks = 0; ks < 2; ++ks) {
#pragma unroll
            for (int db = 0; db < 8; ++db) {
                int vrow = db * 16 + l16;
                int vpos = (ks * 4 + quad) ^ (l16 & 7);
                bf16x8 vf = *(const bf16x8*)&Vt[vrow * 128 + vpos * 16];
                oacc[db] = __builtin_amdgcn_mfma_f32_16x16x32_bf16(pf[ks], vf, oacc[db], 0, 0, 0);
            }
        }

        __syncthreads();

        if (more) {
            const int vcol = (kb + 1) * 64;
#pragma unroll
            for (int t = 0; t < 4; ++t) {
                int c = wave * 256 + t * 64 + lane;
                int vrow = c >> 3, vpos = c & 7;
                gload_lds16(Vtp + (size_t)vrow * S_ + vcol + (vpos ^ (vrow & 7)) * 8,
                            &Vt[(wave * 256 + t * 64) * 16]);
            }
        }
    }

    float lr[4];
#pragma unroll
    for (int r = 0; r < 4; ++r)
        lr[r] = __shfl(li, quad * 4 + r);
#pragma unroll
    for (int db = 0; db < 8; ++db)
#pragma unroll
        for (int r = 0; r < 4; ++r) {
            float v = oacc[db][r] / lr[r];
            size_t row = (size_t)b * S_ + qrow + quad * 4 + r;
            O[row * H_ + h * HD_ + db * 16 + l16] = __float2bfloat16(v);
        }
}

// ---------------------------------------------------------------- launcher
extern "C" void kernel_launch(void* const* d_in, const int* in_sizes, int n_in,
                              void* d_out, int out_size, void* d_ws, size_t ws_size,
                              hipStream_t stream)
{
    const float* hs = (const float*)d_in[0];
    const float* Wq = (const float*)d_in[2];
    const float* bq = (const float*)d_in[3];
    const float* Wk = (const float*)d_in[4];
    const float* bk = (const float*)d_in[5];
    const float* Wv = (const float*)d_in[6];
    const float* bv = (const float*)d_in[7];
    const float* Wo = (const float*)d_in[8];
    const float* bo = (const float*)d_in[9];

    const size_t szX = (size_t)MTOT * H_;
    const size_t szW = (size_t)H_ * H_;

    __hip_bfloat16* Xbf = (__hip_bfloat16*)d_ws;   // reused as attention output
    __hip_bfloat16* Wqb = Xbf + szX;
    __hip_bfloat16* Wkb = Wqb + szW;
    __hip_bfloat16* Wvb = Wkb + szW;
    __hip_bfloat16* Wob = Wvb + szW;
    __hip_bfloat16* Qb  = Wob + szW;
    __hip_bfloat16* Kb  = Qb + szX;
    __hip_bfloat16* VTb = Kb + szX;                // V^T [(b*16+h)*128+d][s]

    castall<<<dim3(4096, 6), 256, 0, stream>>>(hs, Wq, Wk, Wv, Wo, Xbf, Wqb, Wkb, Wvb, Wob);

    gemm_qkv8<<<dim3(384), 512, 0, stream>>>(Xbf, Wqb, Wkb, Wvb, bq, bk, bv, Qb, Kb, VTb);

    attn_kernel<<<dim3(1024), 256, 0, stream>>>(Qb, Kb, VTb, Xbf);

    gemm_out<<<dim3(16, 32), 256, 0, stream>>>(Xbf, Wob, bo, (float*)d_out);
}